// Round 1
// baseline (222.964 us; speedup 1.0000x reference)
//
#include <hip/hip_runtime.h>
#include <math.h>

#define FT_IN  40960
#define FFT_IN 640
#define FT_OUT 256
#define NA     30

// One wave (64 lanes) per board. Lane l owns float4 at dims [4l, 4l+4).
// Each gathered row read = 64 lanes x 16B = 1KB coalesced transaction.
__global__ __launch_bounds__(256) void nnue_fwd(
    const int* __restrict__ stm_idx, const int* __restrict__ nstm_idx,
    const int* __restrict__ f_stm_idx, const int* __restrict__ f_nstm_idx,
    const float* __restrict__ ft_w, const float* __restrict__ ft_b,
    const float* __restrict__ fft_w, const float* __restrict__ fft_b,
    const float* __restrict__ out_w, const float* __restrict__ out_b,
    float* __restrict__ out, int n_boards)
{
    const int board = (int)((blockIdx.x * blockDim.x + threadIdx.x) >> 6);
    const int lane  = (int)(threadIdx.x & 63);
    if (board >= n_boards) return;
    const int col = lane << 2;   // 4 floats per lane, 64 lanes = 256 dims

    const float4 ftb  = *(const float4*)(ft_b  + col);
    const float4 fftb = *(const float4*)(fft_b + col);

    // acc0 = stm half (dims 0..255), acc1 = nstm half (dims 256..511)
    float a0x = ftb.x + fftb.x, a0y = ftb.y + fftb.y,
          a0z = ftb.z + fftb.z, a0w = ftb.w + fftb.w;
    float a1x = a0x, a1y = a0y, a1z = a0z, a1w = a0w;

    const int* si  = stm_idx    + (size_t)board * NA;
    const int* ni  = nstm_idx   + (size_t)board * NA;
    const int* fsi = f_stm_idx  + (size_t)board * NA;
    const int* fni = f_nstm_idx + (size_t)board * NA;

    #pragma unroll 5
    for (int a = 0; a < NA; ++a) {
        const float4 r0 = *(const float4*)(ft_w  + (size_t)si[a]  * FT_OUT + col);
        const float4 r1 = *(const float4*)(ft_w  + (size_t)ni[a]  * FT_OUT + col);
        const float4 r2 = *(const float4*)(fft_w + (size_t)fsi[a] * FT_OUT + col);
        const float4 r3 = *(const float4*)(fft_w + (size_t)fni[a] * FT_OUT + col);
        a0x += r0.x; a0y += r0.y; a0z += r0.z; a0w += r0.w;
        a1x += r1.x; a1y += r1.y; a1z += r1.z; a1w += r1.w;
        a0x += r2.x; a0y += r2.y; a0z += r2.z; a0w += r2.w;
        a1x += r3.x; a1y += r3.y; a1z += r3.z; a1w += r3.w;
    }

    // clip(merge, 0, 1)
    a0x = fminf(fmaxf(a0x, 0.f), 1.f); a0y = fminf(fmaxf(a0y, 0.f), 1.f);
    a0z = fminf(fmaxf(a0z, 0.f), 1.f); a0w = fminf(fmaxf(a0w, 0.f), 1.f);
    a1x = fminf(fmaxf(a1x, 0.f), 1.f); a1y = fminf(fmaxf(a1y, 0.f), 1.f);
    a1z = fminf(fmaxf(a1z, 0.f), 1.f); a1w = fminf(fmaxf(a1w, 0.f), 1.f);

    // dot with out_w[512]: first 256 = stm half, next 256 = nstm half
    const float4 w0 = *(const float4*)(out_w + col);
    const float4 w1 = *(const float4*)(out_w + FT_OUT + col);
    float p = a0x * w0.x + a0y * w0.y + a0z * w0.z + a0w * w0.w
            + a1x * w1.x + a1y * w1.y + a1z * w1.z + a1w * w1.w;

    // wave-64 reduce
    #pragma unroll
    for (int off = 32; off > 0; off >>= 1)
        p += __shfl_down(p, off, 64);

    if (lane == 0) {
        float z = p + out_b[0];
        out[board] = 1.0f / (1.0f + expf(-z));
    }
}

extern "C" void kernel_launch(void* const* d_in, const int* in_sizes, int n_in,
                              void* d_out, int out_size, void* d_ws, size_t ws_size,
                              hipStream_t stream) {
    const int*   stm_idx    = (const int*)d_in[0];
    const int*   nstm_idx   = (const int*)d_in[1];
    const int*   f_stm_idx  = (const int*)d_in[2];
    const int*   f_nstm_idx = (const int*)d_in[3];
    const float* ft_w  = (const float*)d_in[4];
    const float* ft_b  = (const float*)d_in[5];
    const float* fft_w = (const float*)d_in[6];
    const float* fft_b = (const float*)d_in[7];
    const float* out_w = (const float*)d_in[8];
    const float* out_b = (const float*)d_in[9];
    float* out = (float*)d_out;

    const int n_boards = in_sizes[0] / NA;         // 16384
    const int waves_per_block = 256 / 64;          // 4 boards per block
    const int grid = (n_boards + waves_per_block - 1) / waves_per_block;

    nnue_fwd<<<grid, 256, 0, stream>>>(stm_idx, nstm_idx, f_stm_idx, f_nstm_idx,
                                       ft_w, ft_b, fft_w, fft_b, out_w, out_b,
                                       out, n_boards);
}

// Round 2
// 194.194 us; speedup vs baseline: 1.1482x; 1.1482x over previous
//
#include <hip/hip_runtime.h>
#include <math.h>

#define FT_IN  40960
#define FFT_IN 640
#define FT_OUT 256
#define NA     30
#define NSLICE 8          // one column-slice per XCD
#define SLICE_W 32        // 256 / 8 dims per slice
#define BPB    16         // boards per block (256 threads / 16 lanes per board)

// ---------- helpers ----------
__device__ __forceinline__ unsigned short f2bf(float x) {
    unsigned int u = __float_as_uint(x);
    unsigned int r = (u + 0x7FFFu + ((u >> 16) & 1u)) >> 16;   // RNE
    return (unsigned short)r;
}
__device__ __forceinline__ float bflo(unsigned int u) { return __uint_as_float(u << 16); }
__device__ __forceinline__ float bfhi(unsigned int u) { return __uint_as_float(u & 0xFFFF0000u); }

// ---------- pass 1: f32 [nrows][256] -> bf16-pair uint [8][nrows][16] ----------
__global__ __launch_bounds__(256) void convert_slice(
    const float* __restrict__ src, unsigned int* __restrict__ dst, int nrows)
{
    size_t t = (size_t)blockIdx.x * blockDim.x + threadIdx.x;  // one uint (2 bf16) per thread
    size_t total = (size_t)nrows * 128;                        // 128 pairs per row
    if (t >= total) return;
    int r  = (int)(t >> 7);
    int pr = (int)(t & 127);      // pair index; col = 2*pr
    int s  = pr >> 4;             // slice
    int d  = pr & 15;             // pair within slice
    float2 v = *(const float2*)(src + (size_t)r * FT_OUT + 2 * pr);
    unsigned int u = ((unsigned int)f2bf(v.y) << 16) | (unsigned int)f2bf(v.x);
    dst[((size_t)s * nrows + r) * 16 + d] = u;
}

// ---------- pass 2: sliced gather+accumulate+partial dot ----------
// block = 256 threads = 16 boards x 16 lanes; slice = blockIdx % 8 (XCD round-robin)
__global__ __launch_bounds__(256) void nnue_gather(
    const int* __restrict__ stm_idx, const int* __restrict__ nstm_idx,
    const int* __restrict__ f_stm_idx, const int* __restrict__ f_nstm_idx,
    const unsigned int* __restrict__ ft, const unsigned int* __restrict__ fft,
    const float* __restrict__ ft_b, const float* __restrict__ fft_b,
    const float* __restrict__ out_w, float* __restrict__ partial, int n_boards)
{
    const int slice = blockIdx.x & (NSLICE - 1);
    const int group = blockIdx.x >> 3;
    const int sub   = threadIdx.x >> 4;     // board within block
    const int d2    = threadIdx.x & 15;     // dim-pair within slice
    const int board = group * BPB + sub;
    if (board >= n_boards) return;
    const int col = slice * SLICE_W + d2 * 2;

    float a0x = ft_b[col]     + fft_b[col];
    float a0y = ft_b[col + 1] + fft_b[col + 1];
    float a1x = a0x, a1y = a0y;

    const unsigned int* ftp  = ft  + (size_t)slice * FT_IN  * 16 + d2;
    const unsigned int* fftp = fft + (size_t)slice * FFT_IN * 16 + d2;
    const int* si  = stm_idx    + (size_t)board * NA;
    const int* ni  = nstm_idx   + (size_t)board * NA;
    const int* fsi = f_stm_idx  + (size_t)board * NA;
    const int* fni = f_nstm_idx + (size_t)board * NA;

    #pragma unroll 6
    for (int a = 0; a < NA; ++a) {
        unsigned int u0 = ftp [(size_t)si[a]  * 16];
        unsigned int u1 = ftp [(size_t)ni[a]  * 16];
        unsigned int u2 = fftp[(size_t)fsi[a] * 16];
        unsigned int u3 = fftp[(size_t)fni[a] * 16];
        a0x += bflo(u0); a0y += bfhi(u0);
        a1x += bflo(u1); a1y += bfhi(u1);
        a0x += bflo(u2); a0y += bfhi(u2);
        a1x += bflo(u3); a1y += bfhi(u3);
    }

    a0x = fminf(fmaxf(a0x, 0.f), 1.f); a0y = fminf(fmaxf(a0y, 0.f), 1.f);
    a1x = fminf(fmaxf(a1x, 0.f), 1.f); a1y = fminf(fmaxf(a1y, 0.f), 1.f);

    float p = a0x * out_w[col] + a0y * out_w[col + 1]
            + a1x * out_w[FT_OUT + col] + a1y * out_w[FT_OUT + col + 1];

    #pragma unroll
    for (int m = 8; m >= 1; m >>= 1) p += __shfl_xor(p, m, 16);

    if (d2 == 0) partial[(size_t)board * NSLICE + slice] = p;
}

// ---------- pass 3: sum 8 partials + sigmoid ----------
__global__ __launch_bounds__(256) void nnue_final(
    const float* __restrict__ partial, const float* __restrict__ out_b,
    float* __restrict__ out, int n)
{
    int b = blockIdx.x * blockDim.x + threadIdx.x;
    if (b >= n) return;
    const float4* p = (const float4*)(partial + (size_t)b * NSLICE);
    float4 x = p[0], y = p[1];
    float z = x.x + x.y + x.z + x.w + y.x + y.y + y.z + y.w + out_b[0];
    out[b] = 1.0f / (1.0f + expf(-z));
}

// ---------- fallback: round-1 direct f32 kernel (if ws too small) ----------
__global__ __launch_bounds__(256) void nnue_fwd_direct(
    const int* __restrict__ stm_idx, const int* __restrict__ nstm_idx,
    const int* __restrict__ f_stm_idx, const int* __restrict__ f_nstm_idx,
    const float* __restrict__ ft_w, const float* __restrict__ ft_b,
    const float* __restrict__ fft_w, const float* __restrict__ fft_b,
    const float* __restrict__ out_w, const float* __restrict__ out_b,
    float* __restrict__ out, int n_boards)
{
    const int board = (int)((blockIdx.x * blockDim.x + threadIdx.x) >> 6);
    const int lane  = (int)(threadIdx.x & 63);
    if (board >= n_boards) return;
    const int col = lane << 2;
    const float4 ftb  = *(const float4*)(ft_b  + col);
    const float4 fftb = *(const float4*)(fft_b + col);
    float a0x = ftb.x + fftb.x, a0y = ftb.y + fftb.y,
          a0z = ftb.z + fftb.z, a0w = ftb.w + fftb.w;
    float a1x = a0x, a1y = a0y, a1z = a0z, a1w = a0w;
    const int* si  = stm_idx    + (size_t)board * NA;
    const int* ni  = nstm_idx   + (size_t)board * NA;
    const int* fsi = f_stm_idx  + (size_t)board * NA;
    const int* fni = f_nstm_idx + (size_t)board * NA;
    #pragma unroll 5
    for (int a = 0; a < NA; ++a) {
        const float4 r0 = *(const float4*)(ft_w  + (size_t)si[a]  * FT_OUT + col);
        const float4 r1 = *(const float4*)(ft_w  + (size_t)ni[a]  * FT_OUT + col);
        const float4 r2 = *(const float4*)(fft_w + (size_t)fsi[a] * FT_OUT + col);
        const float4 r3 = *(const float4*)(fft_w + (size_t)fni[a] * FT_OUT + col);
        a0x += r0.x + r2.x; a0y += r0.y + r2.y; a0z += r0.z + r2.z; a0w += r0.w + r2.w;
        a1x += r1.x + r3.x; a1y += r1.y + r3.y; a1z += r1.z + r3.z; a1w += r1.w + r3.w;
    }
    a0x = fminf(fmaxf(a0x, 0.f), 1.f); a0y = fminf(fmaxf(a0y, 0.f), 1.f);
    a0z = fminf(fmaxf(a0z, 0.f), 1.f); a0w = fminf(fmaxf(a0w, 0.f), 1.f);
    a1x = fminf(fmaxf(a1x, 0.f), 1.f); a1y = fminf(fmaxf(a1y, 0.f), 1.f);
    a1z = fminf(fmaxf(a1z, 0.f), 1.f); a1w = fminf(fmaxf(a1w, 0.f), 1.f);
    const float4 w0 = *(const float4*)(out_w + col);
    const float4 w1 = *(const float4*)(out_w + FT_OUT + col);
    float p = a0x * w0.x + a0y * w0.y + a0z * w0.z + a0w * w0.w
            + a1x * w1.x + a1y * w1.y + a1z * w1.z + a1w * w1.w;
    #pragma unroll
    for (int off = 32; off > 0; off >>= 1) p += __shfl_down(p, off, 64);
    if (lane == 0) out[board] = 1.0f / (1.0f + expf(-(p + out_b[0])));
}

extern "C" void kernel_launch(void* const* d_in, const int* in_sizes, int n_in,
                              void* d_out, int out_size, void* d_ws, size_t ws_size,
                              hipStream_t stream) {
    const int*   stm_idx    = (const int*)d_in[0];
    const int*   nstm_idx   = (const int*)d_in[1];
    const int*   f_stm_idx  = (const int*)d_in[2];
    const int*   f_nstm_idx = (const int*)d_in[3];
    const float* ft_w  = (const float*)d_in[4];
    const float* ft_b  = (const float*)d_in[5];
    const float* fft_w = (const float*)d_in[6];
    const float* fft_b = (const float*)d_in[7];
    const float* out_w = (const float*)d_in[8];
    const float* out_b = (const float*)d_in[9];
    float* out = (float*)d_out;

    const int n_boards = in_sizes[0] / NA;

    const size_t ft_bytes   = (size_t)FT_IN  * FT_OUT * 2;              // 20.97 MB
    const size_t fft_bytes  = (size_t)FFT_IN * FT_OUT * 2;              // 320 KB
    const size_t part_bytes = (size_t)n_boards * NSLICE * sizeof(float);
    const size_t need = ft_bytes + fft_bytes + part_bytes;

    if (ws_size < need) {
        // fallback: direct f32 gather
        const int grid = (n_boards + 3) / 4;
        nnue_fwd_direct<<<grid, 256, 0, stream>>>(stm_idx, nstm_idx, f_stm_idx, f_nstm_idx,
                                                  ft_w, ft_b, fft_w, fft_b, out_w, out_b,
                                                  out, n_boards);
        return;
    }

    unsigned int* ws_ft   = (unsigned int*)d_ws;
    unsigned int* ws_fft  = (unsigned int*)((char*)d_ws + ft_bytes);
    float*        ws_part = (float*)((char*)d_ws + ft_bytes + fft_bytes);

    {   // pass 1: convert both tables to sliced bf16
        size_t tot = (size_t)FT_IN * 128;
        convert_slice<<<(unsigned)((tot + 255) / 256), 256, 0, stream>>>(ft_w, ws_ft, FT_IN);
        size_t tot2 = (size_t)FFT_IN * 128;
        convert_slice<<<(unsigned)((tot2 + 255) / 256), 256, 0, stream>>>(fft_w, ws_fft, FFT_IN);
    }

    {   // pass 2: sliced gather (8 blocks per 16-board group, one slice each)
        int groups = (n_boards + BPB - 1) / BPB;
        nnue_gather<<<groups * NSLICE, 256, 0, stream>>>(
            stm_idx, nstm_idx, f_stm_idx, f_nstm_idx,
            ws_ft, ws_fft, ft_b, fft_b, out_w, ws_part, n_boards);
    }

    {   // pass 3: reduce partials + sigmoid
        nnue_final<<<(n_boards + 255) / 256, 256, 0, stream>>>(ws_part, out_b, out, n_boards);
    }
}

// Round 3
// 181.459 us; speedup vs baseline: 1.2287x; 1.0702x over previous
//
#include <hip/hip_runtime.h>
#include <math.h>

#define FT_IN  40960
#define FFT_IN 640
#define FT_OUT 256
#define NA     30
#define NSLICE 8          // one column-slice per XCD (blockIdx % 8 -> XCD round-robin)
#define SLICE_W 32        // 256 / 8 dims per slice (64 B in bf16)
#define LPB    4          // lanes per board (each lane owns 8 cols = 16 B)
#define BPB    64         // boards per 256-thread block

// ---------- helpers ----------
__device__ __forceinline__ unsigned short f2bf(float x) {
    unsigned int u = __float_as_uint(x);
    unsigned int r = (u + 0x7FFFu + ((u >> 16) & 1u)) >> 16;   // RNE
    return (unsigned short)r;
}
__device__ __forceinline__ float bflo(unsigned int u) { return __uint_as_float(u << 16); }
__device__ __forceinline__ float bfhi(unsigned int u) { return __uint_as_float(u & 0xFFFF0000u); }

// ---------- pass 0: pack 4 index streams into pre-shifted byte-offset int4 ----------
__global__ __launch_bounds__(256) void pack_idx(
    const int* __restrict__ stm_idx, const int* __restrict__ nstm_idx,
    const int* __restrict__ f_stm_idx, const int* __restrict__ f_nstm_idx,
    int4* __restrict__ pidx, int total)   // total = n_boards * NA
{
    int t = blockIdx.x * blockDim.x + threadIdx.x;
    if (t >= total) return;
    int4 v;
    v.x = stm_idx[t]    << 6;   // * 64 B per sliced bf16 row
    v.y = nstm_idx[t]   << 6;
    v.z = f_stm_idx[t]  << 6;
    v.w = f_nstm_idx[t] << 6;
    pidx[t] = v;
}

// ---------- pass 1: f32 [nrows][256] -> bf16 sliced [8][nrows][16 uints] ----------
// thread: reads 32 B (2 x float4), writes 16 B (uint4)
__global__ __launch_bounds__(256) void convert_slice(
    const float* __restrict__ src, unsigned int* __restrict__ dst, int nrows)
{
    int t = blockIdx.x * blockDim.x + threadIdx.x;
    int total = nrows * 32;               // 32 uint4-chunks per row
    if (t >= total) return;
    int r = t >> 5;
    int g = t & 31;                       // chunk within row: cols [8g, 8g+8)
    int s = g >> 2;                       // slice
    int d = g & 3;                        // uint4 within slice
    const float4* sp = (const float4*)(src + (size_t)r * FT_OUT + g * 8);
    float4 v0 = sp[0], v1 = sp[1];
    uint4 u;
    u.x = ((unsigned)f2bf(v0.y) << 16) | f2bf(v0.x);
    u.y = ((unsigned)f2bf(v0.w) << 16) | f2bf(v0.z);
    u.z = ((unsigned)f2bf(v1.y) << 16) | f2bf(v1.x);
    u.w = ((unsigned)f2bf(v1.w) << 16) | f2bf(v1.z);
    ((uint4*)dst)[((size_t)s * nrows + r) * 4 + d] = u;
}

// ---------- pass 2: sliced gather + accumulate + partial dot ----------
// 256 threads = 64 boards x 4 lanes; lane owns 8 cols (one dwordx4 per gather)
__global__ __launch_bounds__(256) void nnue_gather(
    const int4* __restrict__ pidx,
    const char* __restrict__ ft, const char* __restrict__ fft,
    const float* __restrict__ ft_b, const float* __restrict__ fft_b,
    const float* __restrict__ out_w, float* __restrict__ partial, int n_boards)
{
    const int slice = blockIdx.x & (NSLICE - 1);
    const int group = blockIdx.x >> 3;
    const int sub   = threadIdx.x >> 2;          // board within block
    const int ql    = threadIdx.x & 3;           // lane within quad
    const int board = group * BPB + sub;
    if (board >= n_boards) return;

    const unsigned lane16 = (unsigned)(ql * 16); // byte offset of this lane's 8 cols
    const int col = slice * SLICE_W + ql * 8;

    const char* ftS  = ft  + (size_t)slice * FT_IN  * 64;
    const char* fftS = fft + (size_t)slice * FFT_IN * 64;
    const int4* ip   = pidx + (size_t)board * NA;

    // accumulators: stm half (a0) and nstm half (a1), 8 cols each
    float a0[8], a1[8];
    {
        const float4* b0 = (const float4*)(ft_b  + col);
        const float4* b1 = (const float4*)(fft_b + col);
        float4 x0 = b0[0], x1 = b0[1], y0 = b1[0], y1 = b1[1];
        a0[0] = x0.x + y0.x; a0[1] = x0.y + y0.y; a0[2] = x0.z + y0.z; a0[3] = x0.w + y0.w;
        a0[4] = x1.x + y1.x; a0[5] = x1.y + y1.y; a0[6] = x1.z + y1.z; a0[7] = x1.w + y1.w;
        #pragma unroll
        for (int j = 0; j < 8; ++j) a1[j] = a0[j];
    }

    #pragma unroll 3
    for (int a = 0; a < NA; ++a) {
        int4 off = ip[a];   // broadcast within quad
        uint4 u0 = *(const uint4*)(ftS  + ((unsigned)off.x + lane16));
        uint4 u1 = *(const uint4*)(ftS  + ((unsigned)off.y + lane16));
        uint4 u2 = *(const uint4*)(fftS + ((unsigned)off.z + lane16));
        uint4 u3 = *(const uint4*)(fftS + ((unsigned)off.w + lane16));
        a0[0] += bflo(u0.x); a0[1] += bfhi(u0.x);
        a0[2] += bflo(u0.y); a0[3] += bfhi(u0.y);
        a0[4] += bflo(u0.z); a0[5] += bfhi(u0.z);
        a0[6] += bflo(u0.w); a0[7] += bfhi(u0.w);
        a1[0] += bflo(u1.x); a1[1] += bfhi(u1.x);
        a1[2] += bflo(u1.y); a1[3] += bfhi(u1.y);
        a1[4] += bflo(u1.z); a1[5] += bfhi(u1.z);
        a1[6] += bflo(u1.w); a1[7] += bfhi(u1.w);
        a0[0] += bflo(u2.x); a0[1] += bfhi(u2.x);
        a0[2] += bflo(u2.y); a0[3] += bfhi(u2.y);
        a0[4] += bflo(u2.z); a0[5] += bfhi(u2.z);
        a0[6] += bflo(u2.w); a0[7] += bfhi(u2.w);
        a1[0] += bflo(u3.x); a1[1] += bfhi(u3.x);
        a1[2] += bflo(u3.y); a1[3] += bfhi(u3.y);
        a1[4] += bflo(u3.z); a1[5] += bfhi(u3.z);
        a1[6] += bflo(u3.w); a1[7] += bfhi(u3.w);
    }

    // clip + dot with out_w (first 256 = stm half, next 256 = nstm half)
    const float4* w0p = (const float4*)(out_w + col);
    const float4* w1p = (const float4*)(out_w + FT_OUT + col);
    float4 w00 = w0p[0], w01 = w0p[1], w10 = w1p[0], w11 = w1p[1];
    float w0[8] = {w00.x, w00.y, w00.z, w00.w, w01.x, w01.y, w01.z, w01.w};
    float w1[8] = {w10.x, w10.y, w10.z, w10.w, w11.x, w11.y, w11.z, w11.w};
    float p = 0.f;
    #pragma unroll
    for (int j = 0; j < 8; ++j) {
        p += fminf(fmaxf(a0[j], 0.f), 1.f) * w0[j];
        p += fminf(fmaxf(a1[j], 0.f), 1.f) * w1[j];
    }

    // reduce across the 4 lanes of the quad
    p += __shfl_xor(p, 1, 64);
    p += __shfl_xor(p, 2, 64);

    if (ql == 0) partial[(size_t)board * NSLICE + slice] = p;
}

// ---------- pass 3: sum 8 partials + sigmoid ----------
__global__ __launch_bounds__(256) void nnue_final(
    const float* __restrict__ partial, const float* __restrict__ out_b,
    float* __restrict__ out, int n)
{
    int b = blockIdx.x * blockDim.x + threadIdx.x;
    if (b >= n) return;
    const float4* p = (const float4*)(partial + (size_t)b * NSLICE);
    float4 x = p[0], y = p[1];
    float z = x.x + x.y + x.z + x.w + y.x + y.y + y.z + y.w + out_b[0];
    out[b] = 1.0f / (1.0f + expf(-z));
}

// ---------- fallback: direct f32 gather (if ws too small) ----------
__global__ __launch_bounds__(256) void nnue_fwd_direct(
    const int* __restrict__ stm_idx, const int* __restrict__ nstm_idx,
    const int* __restrict__ f_stm_idx, const int* __restrict__ f_nstm_idx,
    const float* __restrict__ ft_w, const float* __restrict__ ft_b,
    const float* __restrict__ fft_w, const float* __restrict__ fft_b,
    const float* __restrict__ out_w, const float* __restrict__ out_b,
    float* __restrict__ out, int n_boards)
{
    const int board = (int)((blockIdx.x * blockDim.x + threadIdx.x) >> 6);
    const int lane  = (int)(threadIdx.x & 63);
    if (board >= n_boards) return;
    const int col = lane << 2;
    const float4 ftb  = *(const float4*)(ft_b  + col);
    const float4 fftb = *(const float4*)(fft_b + col);
    float a0x = ftb.x + fftb.x, a0y = ftb.y + fftb.y,
          a0z = ftb.z + fftb.z, a0w = ftb.w + fftb.w;
    float a1x = a0x, a1y = a0y, a1z = a0z, a1w = a0w;
    const int* si  = stm_idx    + (size_t)board * NA;
    const int* ni  = nstm_idx   + (size_t)board * NA;
    const int* fsi = f_stm_idx  + (size_t)board * NA;
    const int* fni = f_nstm_idx + (size_t)board * NA;
    #pragma unroll 5
    for (int a = 0; a < NA; ++a) {
        const float4 r0 = *(const float4*)(ft_w  + (size_t)si[a]  * FT_OUT + col);
        const float4 r1 = *(const float4*)(ft_w  + (size_t)ni[a]  * FT_OUT + col);
        const float4 r2 = *(const float4*)(fft_w + (size_t)fsi[a] * FT_OUT + col);
        const float4 r3 = *(const float4*)(fft_w + (size_t)fni[a] * FT_OUT + col);
        a0x += r0.x + r2.x; a0y += r0.y + r2.y; a0z += r0.z + r2.z; a0w += r0.w + r2.w;
        a1x += r1.x + r3.x; a1y += r1.y + r3.y; a1z += r1.z + r3.z; a1w += r1.w + r3.w;
    }
    a0x = fminf(fmaxf(a0x, 0.f), 1.f); a0y = fminf(fmaxf(a0y, 0.f), 1.f);
    a0z = fminf(fmaxf(a0z, 0.f), 1.f); a0w = fminf(fmaxf(a0w, 0.f), 1.f);
    a1x = fminf(fmaxf(a1x, 0.f), 1.f); a1y = fminf(fmaxf(a1y, 0.f), 1.f);
    a1z = fminf(fmaxf(a1z, 0.f), 1.f); a1w = fminf(fmaxf(a1w, 0.f), 1.f);
    const float4 w0 = *(const float4*)(out_w + col);
    const float4 w1 = *(const float4*)(out_w + FT_OUT + col);
    float p = a0x * w0.x + a0y * w0.y + a0z * w0.z + a0w * w0.w
            + a1x * w1.x + a1y * w1.y + a1z * w1.z + a1w * w1.w;
    #pragma unroll
    for (int off = 32; off > 0; off >>= 1) p += __shfl_down(p, off, 64);
    if (lane == 0) out[board] = 1.0f / (1.0f + expf(-(p + out_b[0])));
}

extern "C" void kernel_launch(void* const* d_in, const int* in_sizes, int n_in,
                              void* d_out, int out_size, void* d_ws, size_t ws_size,
                              hipStream_t stream) {
    const int*   stm_idx    = (const int*)d_in[0];
    const int*   nstm_idx   = (const int*)d_in[1];
    const int*   f_stm_idx  = (const int*)d_in[2];
    const int*   f_nstm_idx = (const int*)d_in[3];
    const float* ft_w  = (const float*)d_in[4];
    const float* ft_b  = (const float*)d_in[5];
    const float* fft_w = (const float*)d_in[6];
    const float* fft_b = (const float*)d_in[7];
    const float* out_w = (const float*)d_in[8];
    const float* out_b = (const float*)d_in[9];
    float* out = (float*)d_out;

    const int n_boards = in_sizes[0] / NA;

    const size_t ft_bytes   = (size_t)FT_IN  * FT_OUT * 2;               // 20.97 MB
    const size_t fft_bytes  = (size_t)FFT_IN * FT_OUT * 2;               // 320 KB
    const size_t pidx_bytes = (size_t)n_boards * NA * sizeof(int4);      // 7.86 MB
    const size_t part_bytes = (size_t)n_boards * NSLICE * sizeof(float); // 512 KB
    const size_t need = ft_bytes + fft_bytes + pidx_bytes + part_bytes;

    if (ws_size < need) {
        const int grid = (n_boards + 3) / 4;
        nnue_fwd_direct<<<grid, 256, 0, stream>>>(stm_idx, nstm_idx, f_stm_idx, f_nstm_idx,
                                                  ft_w, ft_b, fft_w, fft_b, out_w, out_b,
                                                  out, n_boards);
        return;
    }

    char* wsp = (char*)d_ws;
    unsigned int* ws_ft   = (unsigned int*)wsp;                wsp += ft_bytes;
    unsigned int* ws_fft  = (unsigned int*)wsp;                wsp += fft_bytes;
    int4*         ws_pidx = (int4*)wsp;                        wsp += pidx_bytes;
    float*        ws_part = (float*)wsp;

    {   // pass 0: pack indices into byte-offset int4
        int total = n_boards * NA;
        pack_idx<<<(total + 255) / 256, 256, 0, stream>>>(
            stm_idx, nstm_idx, f_stm_idx, f_nstm_idx, ws_pidx, total);
    }
    {   // pass 1: convert both tables to sliced bf16
        int tot = FT_IN * 32;
        convert_slice<<<(tot + 255) / 256, 256, 0, stream>>>(ft_w, ws_ft, FT_IN);
        int tot2 = FFT_IN * 32;
        convert_slice<<<(tot2 + 255) / 256, 256, 0, stream>>>(fft_w, ws_fft, FFT_IN);
    }
    {   // pass 2: sliced gather
        int groups = (n_boards + BPB - 1) / BPB;
        nnue_gather<<<groups * NSLICE, 256, 0, stream>>>(
            ws_pidx, (const char*)ws_ft, (const char*)ws_fft,
            ft_b, fft_b, out_w, ws_part, n_boards);
    }
    {   // pass 3: reduce partials + sigmoid
        nnue_final<<<(n_boards + 255) / 256, 256, 0, stream>>>(ws_part, out_b, out, n_boards);
    }
}

// Round 4
// 181.056 us; speedup vs baseline: 1.2315x; 1.0022x over previous
//
#include <hip/hip_runtime.h>
#include <math.h>

#define FT_IN  40960
#define FFT_IN 640
#define FT_OUT 256
#define NA     30
#define NSLICE 8          // one 32-col slice per XCD (blockIdx % 8 -> XCD round-robin)
#define BPB    64         // boards per gather block (256 thr = 64 boards x 4 lanes)

typedef _Float16 h2 __attribute__((ext_vector_type(2)));

__device__ __forceinline__ h2 u2h2(unsigned u) {
    union { unsigned u; h2 h; } c; c.u = u; return c.h;
}
__device__ __forceinline__ unsigned pkh(float a, float b) {
    union { h2 h; unsigned u; } c; c.h = h2{(_Float16)a, (_Float16)b}; return c.u;
}

// ---------- fused prep: f32->f16 sliced convert (ft, fft) + index pack ----------
// sliced layout: [NSLICE][nrows][32 f16] ; row slice = 64 B
__device__ __forceinline__ void conv_block(const float* __restrict__ src,
                                           unsigned* __restrict__ dst,
                                           int nrows, int bid, int tid)
{
    int t = bid * 256 + tid;
    int total = nrows * 32;               // 32 uint4 chunks per row
    if (t >= total) return;
    int r = t >> 5, g = t & 31;           // chunk g: cols [8g, 8g+8)
    int s = g >> 2, d = g & 3;            // slice, uint4-within-slice
    const float4* sp = (const float4*)(src + (size_t)r * FT_OUT + g * 8);
    float4 v0 = sp[0], v1 = sp[1];
    uint4 u;
    u.x = pkh(v0.x, v0.y); u.y = pkh(v0.z, v0.w);
    u.z = pkh(v1.x, v1.y); u.w = pkh(v1.z, v1.w);
    ((uint4*)dst)[((size_t)s * nrows + r) * 4 + d] = u;
}

__global__ __launch_bounds__(256) void prep(
    const float* __restrict__ ft_w, const float* __restrict__ fft_w,
    const int* __restrict__ stm, const int* __restrict__ nstm,
    const int* __restrict__ fstm, const int* __restrict__ fnstm,
    unsigned* __restrict__ ft_o, unsigned* __restrict__ fft_o,
    ushort4* __restrict__ pidx, int n_boards, int nb_ft, int nb_fft)
{
    int bid = blockIdx.x;
    if (bid < nb_ft) {
        conv_block(ft_w, ft_o, FT_IN, bid, threadIdx.x);
    } else if (bid < nb_ft + nb_fft) {
        conv_block(fft_w, fft_o, FFT_IN, bid - nb_ft, threadIdx.x);
    } else {
        int t = (bid - nb_ft - nb_fft) * 256 + (int)threadIdx.x;
        int total = n_boards * NA;
        if (t < total) {
            int board = t / NA, a = t - board * NA;
            ushort4 v;
            v.x = (unsigned short)stm[t];  v.y = (unsigned short)nstm[t];
            v.z = (unsigned short)fstm[t]; v.w = (unsigned short)fnstm[t];
            pidx[(size_t)a * n_boards + board] = v;   // transposed [a][board]
        }
    }
}

// ---------- gather: LDS-staged indices + f16 packed accumulate ----------
__global__ __launch_bounds__(256, 8) void nnue_gather(
    const uint2* __restrict__ pidx,      // [NA][n_boards], each = packed ushort4
    const char* __restrict__ ft, const char* __restrict__ fft,
    const float* __restrict__ ft_b, const float* __restrict__ fft_b,
    const float* __restrict__ out_w, float* __restrict__ partial, int n_boards)
{
    __shared__ uint2 lidx[NA * BPB];     // 15 KB
    const int slice = blockIdx.x & (NSLICE - 1);
    const int group = blockIdx.x >> 3;
    const int tid = (int)threadIdx.x;

    for (int i = tid; i < NA * BPB; i += 256) {
        int a = i >> 6, b = i & 63;
        int bd = group * BPB + b;
        if (bd < n_boards)
            lidx[i] = pidx[(size_t)a * n_boards + bd];
    }
    __syncthreads();

    const int sub = tid >> 2, ql = tid & 3;
    const int board = group * BPB + sub;
    if (board >= n_boards) return;
    const int col = slice * 32 + ql * 8;

    const char* ftS  = ft  + (size_t)slice * FT_IN  * 64 + ql * 16;
    const char* fftS = fft + (size_t)slice * FFT_IN * 64 + ql * 16;

    h2 z = h2{(_Float16)0.f, (_Float16)0.f};
    h2 a0[4] = {z, z, z, z};     // stm half (cols col..col+7)
    h2 a1[4] = {z, z, z, z};     // nstm half

    uint2 iv = lidx[sub];        // a = 0, broadcast within quad
    #pragma unroll 6
    for (int a = 0; a < NA; ++a) {
        uint2 nx = lidx[(a + 1 < NA ? a + 1 : a) * BPB + sub];  // prefetch next idx
        unsigned ox = (iv.x & 0xFFFFu) << 6;
        unsigned oy = (iv.x >> 16) << 6;
        unsigned oz = (iv.y & 0xFFFFu) << 6;
        unsigned ow = (iv.y >> 16) << 6;
        uint4 u0 = *(const uint4*)(ftS  + ox);
        uint4 u1 = *(const uint4*)(ftS  + oy);
        uint4 u2 = *(const uint4*)(fftS + oz);
        uint4 u3 = *(const uint4*)(fftS + ow);
        a0[0] += u2h2(u0.x); a0[1] += u2h2(u0.y); a0[2] += u2h2(u0.z); a0[3] += u2h2(u0.w);
        a1[0] += u2h2(u1.x); a1[1] += u2h2(u1.y); a1[2] += u2h2(u1.z); a1[3] += u2h2(u1.w);
        a0[0] += u2h2(u2.x); a0[1] += u2h2(u2.y); a0[2] += u2h2(u2.z); a0[3] += u2h2(u2.w);
        a1[0] += u2h2(u3.x); a1[1] += u2h2(u3.y); a1[2] += u2h2(u3.z); a1[3] += u2h2(u3.w);
        iv = nx;
    }

    // epilogue: f32 bias + clip + partial dot
    float h0[8], h1[8];
    #pragma unroll
    for (int j = 0; j < 4; ++j) {
        h0[2*j] = (float)a0[j].x; h0[2*j+1] = (float)a0[j].y;
        h1[2*j] = (float)a1[j].x; h1[2*j+1] = (float)a1[j].y;
    }
    const float4* bfp = (const float4*)(ft_b  + col);
    const float4* bgp = (const float4*)(fft_b + col);
    float4 bf0 = bfp[0], bf1 = bfp[1], bg0 = bgp[0], bg1 = bgp[1];
    float bias[8] = {bf0.x+bg0.x, bf0.y+bg0.y, bf0.z+bg0.z, bf0.w+bg0.w,
                     bf1.x+bg1.x, bf1.y+bg1.y, bf1.z+bg1.z, bf1.w+bg1.w};
    const float4* w0p = (const float4*)(out_w + col);
    const float4* w1p = (const float4*)(out_w + FT_OUT + col);
    float4 w00 = w0p[0], w01 = w0p[1], w10 = w1p[0], w11 = w1p[1];
    float w0[8] = {w00.x, w00.y, w00.z, w00.w, w01.x, w01.y, w01.z, w01.w};
    float w1[8] = {w10.x, w10.y, w10.z, w10.w, w11.x, w11.y, w11.z, w11.w};

    float p = 0.f;
    #pragma unroll
    for (int j = 0; j < 8; ++j) {
        p += fminf(fmaxf(h0[j] + bias[j], 0.f), 1.f) * w0[j];
        p += fminf(fmaxf(h1[j] + bias[j], 0.f), 1.f) * w1[j];
    }
    p += __shfl_xor(p, 1, 64);
    p += __shfl_xor(p, 2, 64);
    if (ql == 0) partial[(size_t)board * NSLICE + slice] = p;
}

// ---------- final: sum 8 partials + sigmoid ----------
__global__ __launch_bounds__(256) void nnue_final(
    const float* __restrict__ partial, const float* __restrict__ out_b,
    float* __restrict__ out, int n)
{
    int b = blockIdx.x * blockDim.x + threadIdx.x;
    if (b >= n) return;
    const float4* p = (const float4*)(partial + (size_t)b * NSLICE);
    float4 x = p[0], y = p[1];
    float z = x.x + x.y + x.z + x.w + y.x + y.y + y.z + y.w + out_b[0];
    out[b] = 1.0f / (1.0f + expf(-z));
}

// ---------- fallback: direct f32 gather (if ws too small) ----------
__global__ __launch_bounds__(256) void nnue_fwd_direct(
    const int* __restrict__ stm_idx, const int* __restrict__ nstm_idx,
    const int* __restrict__ f_stm_idx, const int* __restrict__ f_nstm_idx,
    const float* __restrict__ ft_w, const float* __restrict__ ft_b,
    const float* __restrict__ fft_w, const float* __restrict__ fft_b,
    const float* __restrict__ out_w, const float* __restrict__ out_b,
    float* __restrict__ out, int n_boards)
{
    const int board = (int)((blockIdx.x * blockDim.x + threadIdx.x) >> 6);
    const int lane  = (int)(threadIdx.x & 63);
    if (board >= n_boards) return;
    const int col = lane << 2;
    const float4 ftb  = *(const float4*)(ft_b  + col);
    const float4 fftb = *(const float4*)(fft_b + col);
    float a0x = ftb.x + fftb.x, a0y = ftb.y + fftb.y,
          a0z = ftb.z + fftb.z, a0w = ftb.w + fftb.w;
    float a1x = a0x, a1y = a0y, a1z = a0z, a1w = a0w;
    const int* si  = stm_idx    + (size_t)board * NA;
    const int* ni  = nstm_idx   + (size_t)board * NA;
    const int* fsi = f_stm_idx  + (size_t)board * NA;
    const int* fni = f_nstm_idx + (size_t)board * NA;
    #pragma unroll 5
    for (int a = 0; a < NA; ++a) {
        const float4 r0 = *(const float4*)(ft_w  + (size_t)si[a]  * FT_OUT + col);
        const float4 r1 = *(const float4*)(ft_w  + (size_t)ni[a]  * FT_OUT + col);
        const float4 r2 = *(const float4*)(fft_w + (size_t)fsi[a] * FT_OUT + col);
        const float4 r3 = *(const float4*)(fft_w + (size_t)fni[a] * FT_OUT + col);
        a0x += r0.x + r2.x; a0y += r0.y + r2.y; a0z += r0.z + r2.z; a0w += r0.w + r2.w;
        a1x += r1.x + r3.x; a1y += r1.y + r3.y; a1z += r1.z + r3.z; a1w += r1.w + r3.w;
    }
    a0x = fminf(fmaxf(a0x, 0.f), 1.f); a0y = fminf(fmaxf(a0y, 0.f), 1.f);
    a0z = fminf(fmaxf(a0z, 0.f), 1.f); a0w = fminf(fmaxf(a0w, 0.f), 1.f);
    a1x = fminf(fmaxf(a1x, 0.f), 1.f); a1y = fminf(fmaxf(a1y, 0.f), 1.f);
    a1z = fminf(fmaxf(a1z, 0.f), 1.f); a1w = fminf(fmaxf(a1w, 0.f), 1.f);
    const float4 w0 = *(const float4*)(out_w + col);
    const float4 w1 = *(const float4*)(out_w + FT_OUT + col);
    float p = a0x * w0.x + a0y * w0.y + a0z * w0.z + a0w * w0.w
            + a1x * w1.x + a1y * w1.y + a1z * w1.z + a1w * w1.w;
    #pragma unroll
    for (int off = 32; off > 0; off >>= 1) p += __shfl_down(p, off, 64);
    if (lane == 0) out[board] = 1.0f / (1.0f + expf(-(p + out_b[0])));
}

extern "C" void kernel_launch(void* const* d_in, const int* in_sizes, int n_in,
                              void* d_out, int out_size, void* d_ws, size_t ws_size,
                              hipStream_t stream) {
    const int*   stm_idx    = (const int*)d_in[0];
    const int*   nstm_idx   = (const int*)d_in[1];
    const int*   f_stm_idx  = (const int*)d_in[2];
    const int*   f_nstm_idx = (const int*)d_in[3];
    const float* ft_w  = (const float*)d_in[4];
    const float* ft_b  = (const float*)d_in[5];
    const float* fft_w = (const float*)d_in[6];
    const float* fft_b = (const float*)d_in[7];
    const float* out_w = (const float*)d_in[8];
    const float* out_b = (const float*)d_in[9];
    float* out = (float*)d_out;

    const int n_boards = in_sizes[0] / NA;

    const size_t ft_bytes   = (size_t)FT_IN  * FT_OUT * 2;               // 20.97 MB f16
    const size_t fft_bytes  = (size_t)FFT_IN * FT_OUT * 2;               // 320 KB
    const size_t pidx_bytes = (size_t)n_boards * NA * sizeof(ushort4);   // 3.93 MB
    const size_t part_bytes = (size_t)n_boards * NSLICE * sizeof(float); // 512 KB
    const size_t need = ft_bytes + fft_bytes + pidx_bytes + part_bytes;

    if (ws_size < need) {
        const int grid = (n_boards + 3) / 4;
        nnue_fwd_direct<<<grid, 256, 0, stream>>>(stm_idx, nstm_idx, f_stm_idx, f_nstm_idx,
                                                  ft_w, ft_b, fft_w, fft_b, out_w, out_b,
                                                  out, n_boards);
        return;
    }

    char* wsp = (char*)d_ws;
    unsigned* ws_ft   = (unsigned*)wsp;            wsp += ft_bytes;
    unsigned* ws_fft  = (unsigned*)wsp;            wsp += fft_bytes;
    ushort4*  ws_pidx = (ushort4*)wsp;             wsp += pidx_bytes;
    float*    ws_part = (float*)wsp;

    {   // fused prep: converts + index pack in one dispatch
        const int nb_ft   = FT_IN  * 32 / 256;               // 5120
        const int nb_fft  = FFT_IN * 32 / 256;               // 80
        const int nb_pack = (n_boards * NA + 255) / 256;     // 1920
        prep<<<nb_ft + nb_fft + nb_pack, 256, 0, stream>>>(
            ft_w, fft_w, stm_idx, nstm_idx, f_stm_idx, f_nstm_idx,
            ws_ft, ws_fft, ws_pidx, n_boards, nb_ft, nb_fft);
    }
    {   // sliced gather
        int groups = (n_boards + BPB - 1) / BPB;
        nnue_gather<<<groups * NSLICE, 256, 0, stream>>>(
            (const uint2*)ws_pidx, (const char*)ws_ft, (const char*)ws_fft,
            ft_b, fft_b, out_w, ws_part, n_boards);
    }
    {   // reduce partials + sigmoid
        nnue_final<<<(n_boards + 255) / 256, 256, 0, stream>>>(ws_part, out_b, out, n_boards);
    }
}

// Round 5
// 168.292 us; speedup vs baseline: 1.3249x; 1.0758x over previous
//
#include <hip/hip_runtime.h>
#include <math.h>

#define FT_IN  40960
#define FFT_IN 640
#define FT_OUT 256
#define NA     30
#define NSLICE 8          // one 32-col slice per XCD (blockIdx % 8 -> XCD round-robin)
#define BPB    128        // boards per gather block (512 thr = 128 boards x 4 lanes)

typedef _Float16 h2 __attribute__((ext_vector_type(2)));

__device__ __forceinline__ h2 u2h2(unsigned u) {
    union { unsigned u; h2 h; } c; c.u = u; return c.h;
}
__device__ __forceinline__ unsigned pkh(float a, float b) {
    union { h2 h; unsigned u; } c; c.h = h2{(_Float16)a, (_Float16)b}; return c.u;
}

// ---------- fused prep: f32->f16 sliced convert (ft, fft) + index pack ----------
// sliced layout: [NSLICE][nrows][32 f16]; one row-slice = 64 B
__device__ __forceinline__ void conv_block(const float* __restrict__ src,
                                           unsigned* __restrict__ dst,
                                           int nrows, int bid, int tid)
{
    int t = bid * 256 + tid;
    int total = nrows * 32;               // 32 uint4 chunks per row
    if (t >= total) return;
    int r = t >> 5, g = t & 31;           // chunk g: cols [8g, 8g+8)
    int s = g >> 2, d = g & 3;            // slice, uint4-within-slice
    const float4* sp = (const float4*)(src + (size_t)r * FT_OUT + g * 8);
    float4 v0 = sp[0], v1 = sp[1];
    uint4 u;
    u.x = pkh(v0.x, v0.y); u.y = pkh(v0.z, v0.w);
    u.z = pkh(v1.x, v1.y); u.w = pkh(v1.z, v1.w);
    ((uint4*)dst)[((size_t)s * nrows + r) * 4 + d] = u;
}

__global__ __launch_bounds__(256) void prep(
    const float* __restrict__ ft_w, const float* __restrict__ fft_w,
    const int* __restrict__ stm, const int* __restrict__ nstm,
    const int* __restrict__ fstm, const int* __restrict__ fnstm,
    unsigned* __restrict__ ft_o, unsigned* __restrict__ fft_o,
    ushort4* __restrict__ pidx, int n_boards, int nb_ft, int nb_fft)
{
    int bid = blockIdx.x;
    if (bid < nb_ft) {
        conv_block(ft_w, ft_o, FT_IN, bid, threadIdx.x);
    } else if (bid < nb_ft + nb_fft) {
        conv_block(fft_w, fft_o, FFT_IN, bid - nb_ft, threadIdx.x);
    } else {
        int t = (bid - nb_ft - nb_fft) * 256 + (int)threadIdx.x;
        int total = n_boards * NA;
        if (t < total) {
            int board = t / NA, a = t - board * NA;
            ushort4 v;
            v.x = (unsigned short)stm[t];  v.y = (unsigned short)nstm[t];
            v.z = (unsigned short)fstm[t]; v.w = (unsigned short)fnstm[t];
            pidx[(size_t)a * n_boards + board] = v;   // transposed [a][board]
        }
    }
}

// ---------- gather: fft in LDS, deep-pipelined ft gathers ----------
// 512 threads = 128 boards x 4 lanes; lane owns 8 cols (16 B) of the 32-col slice
__global__ __launch_bounds__(512, 4) void nnue_gather(
    const unsigned long long* __restrict__ pidx,  // [NA][n_boards] packed ushort4
    const char* __restrict__ ft, const char* __restrict__ fft,
    const float* __restrict__ ft_b, const float* __restrict__ fft_b,
    const float* __restrict__ out_w, float* __restrict__ partial, int n_boards)
{
    __shared__ uint4 lfft[FFT_IN * 4];    // 40 KB, chunk-swizzled fft slice
    const int slice = blockIdx.x & (NSLICE - 1);
    const int group = blockIdx.x >> 3;
    const int tid = (int)threadIdx.x;

    // stage fft slice into LDS; chunk c of row r stored at position (c+r)&3
    {
        const uint4* fsrc = (const uint4*)(fft + (size_t)slice * FFT_IN * 64);
        for (int i = tid; i < FFT_IN * 4; i += 512) {
            int r = i >> 2, c = i & 3;
            lfft[(r << 2) + ((c + r) & 3)] = fsrc[i];
        }
    }
    __syncthreads();

    const int sub = tid >> 2, ql = tid & 3;
    int board = group * BPB + sub;
    const bool active = board < n_boards;
    if (!active) board = n_boards - 1;

    const char* ftS = ft + (size_t)slice * FT_IN * 64 + ql * 16;
    const int col = slice * 32 + ql * 8;

    h2 z = h2{(_Float16)0.f, (_Float16)0.f};
    h2 a0[4] = {z, z, z, z};     // stm half
    h2 a1[4] = {z, z, z, z};     // nstm half

    // pipeline: indices 6 ahead, ft loads 3 ahead
    unsigned long long iv[6];
    #pragma unroll
    for (int a = 0; a < 6; ++a)
        iv[a] = __builtin_nontemporal_load(pidx + (size_t)a * n_boards + board);

    uint4 fs[3], fn[3];
    #pragma unroll
    for (int a = 0; a < 3; ++a) {
        unsigned lo = (unsigned)iv[a];
        fs[a] = *(const uint4*)(ftS + ((lo & 0xFFFFu) << 6));
        fn[a] = *(const uint4*)(ftS + ((lo >> 16) << 6));
    }

    #pragma unroll
    for (int a = 0; a < NA; ++a) {
        const int k = a % 3;
        const int j = a % 6;
        // fft rows from LDS (issue early; lgkm wait overlaps ft pk-adds)
        unsigned hi = (unsigned)(iv[j] >> 32);
        unsigned rz = hi & 0xFFFFu, rw = hi >> 16;
        uint4 g0 = lfft[(rz << 2) + ((ql + rz) & 3)];
        uint4 g1 = lfft[(rw << 2) + ((ql + rw) & 3)];
        // consume ft stage k
        uint4 u0 = fs[k], u1 = fn[k];
        a0[0] += u2h2(u0.x); a0[1] += u2h2(u0.y); a0[2] += u2h2(u0.z); a0[3] += u2h2(u0.w);
        a1[0] += u2h2(u1.x); a1[1] += u2h2(u1.y); a1[2] += u2h2(u1.z); a1[3] += u2h2(u1.w);
        a0[0] += u2h2(g0.x); a0[1] += u2h2(g0.y); a0[2] += u2h2(g0.z); a0[3] += u2h2(g0.w);
        a1[0] += u2h2(g1.x); a1[1] += u2h2(g1.y); a1[2] += u2h2(g1.z); a1[3] += u2h2(g1.w);
        // refill: idx a+6, ft loads a+3 (their idx arrived 3 iters ago)
        if (a + 6 < NA)
            iv[j] = __builtin_nontemporal_load(pidx + (size_t)(a + 6) * n_boards + board);
        if (a + 3 < NA) {
            unsigned lo = (unsigned)iv[(a + 3) % 6];
            fs[k] = *(const uint4*)(ftS + ((lo & 0xFFFFu) << 6));
            fn[k] = *(const uint4*)(ftS + ((lo >> 16) << 6));
        }
    }

    // epilogue: f32 bias + clip + partial dot
    float h0[8], h1[8];
    #pragma unroll
    for (int i = 0; i < 4; ++i) {
        h0[2*i] = (float)a0[i].x; h0[2*i+1] = (float)a0[i].y;
        h1[2*i] = (float)a1[i].x; h1[2*i+1] = (float)a1[i].y;
    }
    const float4* bfp = (const float4*)(ft_b  + col);
    const float4* bgp = (const float4*)(fft_b + col);
    float4 bf0 = bfp[0], bf1 = bfp[1], bg0 = bgp[0], bg1 = bgp[1];
    float bias[8] = {bf0.x+bg0.x, bf0.y+bg0.y, bf0.z+bg0.z, bf0.w+bg0.w,
                     bf1.x+bg1.x, bf1.y+bg1.y, bf1.z+bg1.z, bf1.w+bg1.w};
    const float4* w0p = (const float4*)(out_w + col);
    const float4* w1p = (const float4*)(out_w + FT_OUT + col);
    float4 w00 = w0p[0], w01 = w0p[1], w10 = w1p[0], w11 = w1p[1];
    float w0[8] = {w00.x, w00.y, w00.z, w00.w, w01.x, w01.y, w01.z, w01.w};
    float w1[8] = {w10.x, w10.y, w10.z, w10.w, w11.x, w11.y, w11.z, w11.w};

    float p = 0.f;
    #pragma unroll
    for (int i = 0; i < 8; ++i) {
        p += fminf(fmaxf(h0[i] + bias[i], 0.f), 1.f) * w0[i];
        p += fminf(fmaxf(h1[i] + bias[i], 0.f), 1.f) * w1[i];
    }
    p += __shfl_xor(p, 1, 64);
    p += __shfl_xor(p, 2, 64);
    // [slice][board] layout -> coalesced 4B stores across subs
    if (active && ql == 0) partial[(size_t)slice * n_boards + board] = p;
}

// ---------- final: sum 8 partials + sigmoid ----------
__global__ __launch_bounds__(256) void nnue_final(
    const float* __restrict__ partial, const float* __restrict__ out_b,
    float* __restrict__ out, int n)
{
    int b = blockIdx.x * blockDim.x + threadIdx.x;
    if (b >= n) return;
    float zv = out_b[0];
    #pragma unroll
    for (int s = 0; s < NSLICE; ++s) zv += partial[(size_t)s * n + b];
    out[b] = 1.0f / (1.0f + expf(-zv));
}

// ---------- fallback: direct f32 gather (if ws too small) ----------
__global__ __launch_bounds__(256) void nnue_fwd_direct(
    const int* __restrict__ stm_idx, const int* __restrict__ nstm_idx,
    const int* __restrict__ f_stm_idx, const int* __restrict__ f_nstm_idx,
    const float* __restrict__ ft_w, const float* __restrict__ ft_b,
    const float* __restrict__ fft_w, const float* __restrict__ fft_b,
    const float* __restrict__ out_w, const float* __restrict__ out_b,
    float* __restrict__ out, int n_boards)
{
    const int board = (int)((blockIdx.x * blockDim.x + threadIdx.x) >> 6);
    const int lane  = (int)(threadIdx.x & 63);
    if (board >= n_boards) return;
    const int col = lane << 2;
    const float4 ftb  = *(const float4*)(ft_b  + col);
    const float4 fftb = *(const float4*)(fft_b + col);
    float a0x = ftb.x + fftb.x, a0y = ftb.y + fftb.y,
          a0z = ftb.z + fftb.z, a0w = ftb.w + fftb.w;
    float a1x = a0x, a1y = a0y, a1z = a0z, a1w = a0w;
    const int* si  = stm_idx    + (size_t)board * NA;
    const int* ni  = nstm_idx   + (size_t)board * NA;
    const int* fsi = f_stm_idx  + (size_t)board * NA;
    const int* fni = f_nstm_idx + (size_t)board * NA;
    #pragma unroll 5
    for (int a = 0; a < NA; ++a) {
        const float4 r0 = *(const float4*)(ft_w  + (size_t)si[a]  * FT_OUT + col);
        const float4 r1 = *(const float4*)(ft_w  + (size_t)ni[a]  * FT_OUT + col);
        const float4 r2 = *(const float4*)(fft_w + (size_t)fsi[a] * FT_OUT + col);
        const float4 r3 = *(const float4*)(fft_w + (size_t)fni[a] * FT_OUT + col);
        a0x += r0.x + r2.x; a0y += r0.y + r2.y; a0z += r0.z + r2.z; a0w += r0.w + r2.w;
        a1x += r1.x + r3.x; a1y += r1.y + r3.y; a1z += r1.z + r3.z; a1w += r1.w + r3.w;
    }
    a0x = fminf(fmaxf(a0x, 0.f), 1.f); a0y = fminf(fmaxf(a0y, 0.f), 1.f);
    a0z = fminf(fmaxf(a0z, 0.f), 1.f); a0w = fminf(fmaxf(a0w, 0.f), 1.f);
    a1x = fminf(fmaxf(a1x, 0.f), 1.f); a1y = fminf(fmaxf(a1y, 0.f), 1.f);
    a1z = fminf(fmaxf(a1z, 0.f), 1.f); a1w = fminf(fmaxf(a1w, 0.f), 1.f);
    const float4 w0 = *(const float4*)(out_w + col);
    const float4 w1 = *(const float4*)(out_w + FT_OUT + col);
    float p = a0x * w0.x + a0y * w0.y + a0z * w0.z + a0w * w0.w
            + a1x * w1.x + a1y * w1.y + a1z * w1.z + a1w * w1.w;
    #pragma unroll
    for (int off = 32; off > 0; off >>= 1) p += __shfl_down(p, off, 64);
    if (lane == 0) out[board] = 1.0f / (1.0f + expf(-(p + out_b[0])));
}

extern "C" void kernel_launch(void* const* d_in, const int* in_sizes, int n_in,
                              void* d_out, int out_size, void* d_ws, size_t ws_size,
                              hipStream_t stream) {
    const int*   stm_idx    = (const int*)d_in[0];
    const int*   nstm_idx   = (const int*)d_in[1];
    const int*   f_stm_idx  = (const int*)d_in[2];
    const int*   f_nstm_idx = (const int*)d_in[3];
    const float* ft_w  = (const float*)d_in[4];
    const float* ft_b  = (const float*)d_in[5];
    const float* fft_w = (const float*)d_in[6];
    const float* fft_b = (const float*)d_in[7];
    const float* out_w = (const float*)d_in[8];
    const float* out_b = (const float*)d_in[9];
    float* out = (float*)d_out;

    const int n_boards = in_sizes[0] / NA;

    const size_t ft_bytes   = (size_t)FT_IN  * FT_OUT * 2;               // 20.97 MB f16
    const size_t fft_bytes  = (size_t)FFT_IN * FT_OUT * 2;               // 320 KB
    const size_t pidx_bytes = (size_t)n_boards * NA * sizeof(ushort4);   // 3.93 MB
    const size_t part_bytes = (size_t)n_boards * NSLICE * sizeof(float); // 512 KB
    const size_t need = ft_bytes + fft_bytes + pidx_bytes + part_bytes;

    if (ws_size < need) {
        const int grid = (n_boards + 3) / 4;
        nnue_fwd_direct<<<grid, 256, 0, stream>>>(stm_idx, nstm_idx, f_stm_idx, f_nstm_idx,
                                                  ft_w, ft_b, fft_w, fft_b, out_w, out_b,
                                                  out, n_boards);
        return;
    }

    char* wsp = (char*)d_ws;
    unsigned* ws_ft   = (unsigned*)wsp;            wsp += ft_bytes;
    unsigned* ws_fft  = (unsigned*)wsp;            wsp += fft_bytes;
    ushort4*  ws_pidx = (ushort4*)wsp;             wsp += pidx_bytes;
    float*    ws_part = (float*)wsp;

    {   // fused prep: converts + index pack in one dispatch
        const int nb_ft   = FT_IN  * 32 / 256;               // 5120
        const int nb_fft  = FFT_IN * 32 / 256;               // 80
        const int nb_pack = (n_boards * NA + 255) / 256;
        prep<<<nb_ft + nb_fft + nb_pack, 256, 0, stream>>>(
            ft_w, fft_w, stm_idx, nstm_idx, f_stm_idx, f_nstm_idx,
            ws_ft, ws_fft, ws_pidx, n_boards, nb_ft, nb_fft);
    }
    {   // sliced gather
        int groups = (n_boards + BPB - 1) / BPB;
        nnue_gather<<<groups * NSLICE, 512, 0, stream>>>(
            (const unsigned long long*)ws_pidx, (const char*)ws_ft, (const char*)ws_fft,
            ft_b, fft_b, out_w, ws_part, n_boards);
    }
    {   // reduce partials + sigmoid
        nnue_final<<<(n_boards + 255) / 256, 256, 0, stream>>>(ws_part, out_b, out, n_boards);
    }
}

// Round 6
// 148.365 us; speedup vs baseline: 1.5028x; 1.1343x over previous
//
#include <hip/hip_runtime.h>
#include <math.h>

#define FT_IN  40960
#define FFT_IN 640
#define FT_OUT 256
#define NA     30
#define NSLICE 8          // one 32-col slice per XCD (blockIdx % 8 -> XCD round-robin)
#define BPB    256        // boards per gather block (1024 thr = 256 boards x 4 lanes)
#define FTD    4          // ft pipeline depth (loads in flight per stream)
#define IDP    8          // index prefetch ring

typedef _Float16 h2 __attribute__((ext_vector_type(2)));

__device__ __forceinline__ h2 u2h2(unsigned u) {
    union { unsigned u; h2 h; } c; c.u = u; return c.h;
}
__device__ __forceinline__ unsigned pkh(float a, float b) {
    union { h2 h; unsigned u; } c; c.h = h2{(_Float16)a, (_Float16)b}; return c.u;
}

// ---------- fused prep: f32->f16 sliced convert (ft, fft) + index pack ----------
// sliced layout: [NSLICE][nrows][32 f16]; one row-slice = 64 B
__device__ __forceinline__ void conv_block(const float* __restrict__ src,
                                           unsigned* __restrict__ dst,
                                           int nrows, int bid, int tid)
{
    int t = bid * 256 + tid;
    int total = nrows * 32;               // 32 uint4 chunks per row
    if (t >= total) return;
    int r = t >> 5, g = t & 31;           // chunk g: cols [8g, 8g+8)
    int s = g >> 2, d = g & 3;            // slice, uint4-within-slice
    const float4* sp = (const float4*)(src + (size_t)r * FT_OUT + g * 8);
    float4 v0 = sp[0], v1 = sp[1];
    uint4 u;
    u.x = pkh(v0.x, v0.y); u.y = pkh(v0.z, v0.w);
    u.z = pkh(v1.x, v1.y); u.w = pkh(v1.z, v1.w);
    ((uint4*)dst)[((size_t)s * nrows + r) * 4 + d] = u;
}

__global__ __launch_bounds__(256) void prep(
    const float* __restrict__ ft_w, const float* __restrict__ fft_w,
    const int* __restrict__ stm, const int* __restrict__ nstm,
    const int* __restrict__ fstm, const int* __restrict__ fnstm,
    unsigned* __restrict__ ft_o, unsigned* __restrict__ fft_o,
    ushort4* __restrict__ pidx, int n_boards, int nb_ft, int nb_fft)
{
    int bid = blockIdx.x;
    if (bid < nb_ft) {
        conv_block(ft_w, ft_o, FT_IN, bid, threadIdx.x);
    } else if (bid < nb_ft + nb_fft) {
        conv_block(fft_w, fft_o, FFT_IN, bid - nb_ft, threadIdx.x);
    } else {
        int t = (bid - nb_ft - nb_fft) * 256 + (int)threadIdx.x;
        int total = n_boards * NA;
        if (t < total) {
            int board = t / NA, a = t - board * NA;
            ushort4 v;
            v.x = (unsigned short)stm[t];  v.y = (unsigned short)nstm[t];
            v.z = (unsigned short)fstm[t]; v.w = (unsigned short)fnstm[t];
            pidx[(size_t)a * n_boards + board] = v;   // transposed [a][board]
        }
    }
}

// ---------- gather: fft in LDS (stride-80B, conflict-free), deep-pipelined ft ----------
// 1024 threads = 256 boards x 4 lanes; lane owns 8 cols (16 B) of the 32-col slice
__global__ __launch_bounds__(1024, 8) void nnue_gather(
    const unsigned long long* __restrict__ pidx,  // [NA][n_boards] packed ushort4
    const char* __restrict__ ft, const char* __restrict__ fft,
    const float* __restrict__ ft_b, const float* __restrict__ fft_b,
    const float* __restrict__ out_w, float* __restrict__ partial, int n_boards)
{
    __shared__ uint4 lfft[FFT_IN * 5];    // 50 KB; row stride 5 uint4 (80 B) breaks bank parity
    const int slice = blockIdx.x & (NSLICE - 1);
    const int group = blockIdx.x >> 3;
    const int tid = (int)threadIdx.x;

    {   // stage fft slice: row r chunk c -> lfft[r*5 + c]
        const uint4* fsrc = (const uint4*)(fft + (size_t)slice * FFT_IN * 64);
        for (int i = tid; i < FFT_IN * 4; i += 1024) {
            int r = i >> 2, c = i & 3;
            lfft[r * 5 + c] = fsrc[i];
        }
    }
    __syncthreads();

    const int sub = tid >> 2, ql = tid & 3;
    int board = group * BPB + sub;
    const bool active = board < n_boards;
    if (!active) board = n_boards - 1;

    const char* ftS = ft + (size_t)slice * FT_IN * 64 + ql * 16;
    const int col = slice * 32 + ql * 8;

    h2 z = h2{(_Float16)0.f, (_Float16)0.f};
    h2 a0[4] = {z, z, z, z};     // stm half
    h2 a1[4] = {z, z, z, z};     // nstm half

    // pipeline: idx ring IDP ahead, ft loads FTD ahead
    unsigned long long iv[IDP];
    #pragma unroll
    for (int a = 0; a < IDP; ++a)
        iv[a] = pidx[(size_t)a * n_boards + board];

    uint4 fs[FTD], fn[FTD];
    #pragma unroll
    for (int a = 0; a < FTD; ++a) {
        unsigned lo = (unsigned)iv[a];
        fs[a] = *(const uint4*)(ftS + ((lo & 0xFFFFu) << 6));
        fn[a] = *(const uint4*)(ftS + ((lo >> 16) << 6));
    }

    #pragma unroll
    for (int a = 0; a < NA; ++a) {
        const int k = a % FTD;
        const int j = a % IDP;
        // fft rows from LDS
        unsigned hi = (unsigned)(iv[j] >> 32);
        unsigned rz = (hi & 0xFFFFu) * 5u, rw = (hi >> 16) * 5u;
        uint4 g0 = lfft[rz + ql];
        uint4 g1 = lfft[rw + ql];
        // consume ft stage k
        uint4 u0 = fs[k], u1 = fn[k];
        a0[0] += u2h2(u0.x); a0[1] += u2h2(u0.y); a0[2] += u2h2(u0.z); a0[3] += u2h2(u0.w);
        a1[0] += u2h2(u1.x); a1[1] += u2h2(u1.y); a1[2] += u2h2(u1.z); a1[3] += u2h2(u1.w);
        a0[0] += u2h2(g0.x); a0[1] += u2h2(g0.y); a0[2] += u2h2(g0.z); a0[3] += u2h2(g0.w);
        a1[0] += u2h2(g1.x); a1[1] += u2h2(g1.y); a1[2] += u2h2(g1.z); a1[3] += u2h2(g1.w);
        // refill: idx a+IDP, ft loads a+FTD (their idx arrived IDP-FTD iters ago)
        if (a + IDP < NA)
            iv[j] = pidx[(size_t)(a + IDP) * n_boards + board];
        if (a + FTD < NA) {
            unsigned lo = (unsigned)iv[(a + FTD) % IDP];
            fs[k] = *(const uint4*)(ftS + ((lo & 0xFFFFu) << 6));
            fn[k] = *(const uint4*)(ftS + ((lo >> 16) << 6));
        }
    }

    // epilogue: f32 bias + clip + partial dot
    float h0[8], h1[8];
    #pragma unroll
    for (int i = 0; i < 4; ++i) {
        h0[2*i] = (float)a0[i].x; h0[2*i+1] = (float)a0[i].y;
        h1[2*i] = (float)a1[i].x; h1[2*i+1] = (float)a1[i].y;
    }
    const float4* bfp = (const float4*)(ft_b  + col);
    const float4* bgp = (const float4*)(fft_b + col);
    float4 bf0 = bfp[0], bf1 = bfp[1], bg0 = bgp[0], bg1 = bgp[1];
    float bias[8] = {bf0.x+bg0.x, bf0.y+bg0.y, bf0.z+bg0.z, bf0.w+bg0.w,
                     bf1.x+bg1.x, bf1.y+bg1.y, bf1.z+bg1.z, bf1.w+bg1.w};
    const float4* w0p = (const float4*)(out_w + col);
    const float4* w1p = (const float4*)(out_w + FT_OUT + col);
    float4 w00 = w0p[0], w01 = w0p[1], w10 = w1p[0], w11 = w1p[1];
    float w0[8] = {w00.x, w00.y, w00.z, w00.w, w01.x, w01.y, w01.z, w01.w};
    float w1[8] = {w10.x, w10.y, w10.z, w10.w, w11.x, w11.y, w11.z, w11.w};

    float p = 0.f;
    #pragma unroll
    for (int i = 0; i < 8; ++i) {
        p += fminf(fmaxf(h0[i] + bias[i], 0.f), 1.f) * w0[i];
        p += fminf(fmaxf(h1[i] + bias[i], 0.f), 1.f) * w1[i];
    }
    p += __shfl_xor(p, 1, 64);
    p += __shfl_xor(p, 2, 64);
    if (active && ql == 0) partial[(size_t)slice * n_boards + board] = p;
}

// ---------- final: sum 8 partials + sigmoid ----------
__global__ __launch_bounds__(256) void nnue_final(
    const float* __restrict__ partial, const float* __restrict__ out_b,
    float* __restrict__ out, int n)
{
    int b = blockIdx.x * blockDim.x + threadIdx.x;
    if (b >= n) return;
    float zv = out_b[0];
    #pragma unroll
    for (int s = 0; s < NSLICE; ++s) zv += partial[(size_t)s * n + b];
    out[b] = 1.0f / (1.0f + expf(-zv));
}

// ---------- fallback: direct f32 gather (if ws too small) ----------
__global__ __launch_bounds__(256) void nnue_fwd_direct(
    const int* __restrict__ stm_idx, const int* __restrict__ nstm_idx,
    const int* __restrict__ f_stm_idx, const int* __restrict__ f_nstm_idx,
    const float* __restrict__ ft_w, const float* __restrict__ ft_b,
    const float* __restrict__ fft_w, const float* __restrict__ fft_b,
    const float* __restrict__ out_w, const float* __restrict__ out_b,
    float* __restrict__ out, int n_boards)
{
    const int board = (int)((blockIdx.x * blockDim.x + threadIdx.x) >> 6);
    const int lane  = (int)(threadIdx.x & 63);
    if (board >= n_boards) return;
    const int col = lane << 2;
    const float4 ftb  = *(const float4*)(ft_b  + col);
    const float4 fftb = *(const float4*)(fft_b + col);
    float a0x = ftb.x + fftb.x, a0y = ftb.y + fftb.y,
          a0z = ftb.z + fftb.z, a0w = ftb.w + fftb.w;
    float a1x = a0x, a1y = a0y, a1z = a0z, a1w = a0w;
    const int* si  = stm_idx    + (size_t)board * NA;
    const int* ni  = nstm_idx   + (size_t)board * NA;
    const int* fsi = f_stm_idx  + (size_t)board * NA;
    const int* fni = f_nstm_idx + (size_t)board * NA;
    #pragma unroll 5
    for (int a = 0; a < NA; ++a) {
        const float4 r0 = *(const float4*)(ft_w  + (size_t)si[a]  * FT_OUT + col);
        const float4 r1 = *(const float4*)(ft_w  + (size_t)ni[a]  * FT_OUT + col);
        const float4 r2 = *(const float4*)(fft_w + (size_t)fsi[a] * FT_OUT + col);
        const float4 r3 = *(const float4*)(fft_w + (size_t)fni[a] * FT_OUT + col);
        a0x += r0.x + r2.x; a0y += r0.y + r2.y; a0z += r0.z + r2.z; a0w += r0.w + r2.w;
        a1x += r1.x + r3.x; a1y += r1.y + r3.y; a1z += r1.z + r3.z; a1w += r1.w + r3.w;
    }
    a0x = fminf(fmaxf(a0x, 0.f), 1.f); a0y = fminf(fmaxf(a0y, 0.f), 1.f);
    a0z = fminf(fmaxf(a0z, 0.f), 1.f); a0w = fminf(fmaxf(a0w, 0.f), 1.f);
    a1x = fminf(fmaxf(a1x, 0.f), 1.f); a1y = fminf(fmaxf(a1y, 0.f), 1.f);
    a1z = fminf(fmaxf(a1z, 0.f), 1.f); a1w = fminf(fmaxf(a1w, 0.f), 1.f);
    const float4 w0 = *(const float4*)(out_w + col);
    const float4 w1 = *(const float4*)(out_w + FT_OUT + col);
    float p = a0x * w0.x + a0y * w0.y + a0z * w0.z + a0w * w0.w
            + a1x * w1.x + a1y * w1.y + a1z * w1.z + a1w * w1.w;
    #pragma unroll
    for (int off = 32; off > 0; off >>= 1) p += __shfl_down(p, off, 64);
    if (lane == 0) out[board] = 1.0f / (1.0f + expf(-(p + out_b[0])));
}

extern "C" void kernel_launch(void* const* d_in, const int* in_sizes, int n_in,
                              void* d_out, int out_size, void* d_ws, size_t ws_size,
                              hipStream_t stream) {
    const int*   stm_idx    = (const int*)d_in[0];
    const int*   nstm_idx   = (const int*)d_in[1];
    const int*   f_stm_idx  = (const int*)d_in[2];
    const int*   f_nstm_idx = (const int*)d_in[3];
    const float* ft_w  = (const float*)d_in[4];
    const float* ft_b  = (const float*)d_in[5];
    const float* fft_w = (const float*)d_in[6];
    const float* fft_b = (const float*)d_in[7];
    const float* out_w = (const float*)d_in[8];
    const float* out_b = (const float*)d_in[9];
    float* out = (float*)d_out;

    const int n_boards = in_sizes[0] / NA;

    const size_t ft_bytes   = (size_t)FT_IN  * FT_OUT * 2;               // 20.97 MB f16
    const size_t fft_bytes  = (size_t)FFT_IN * FT_OUT * 2;               // 320 KB
    const size_t pidx_bytes = (size_t)n_boards * NA * sizeof(ushort4);   // 3.93 MB
    const size_t part_bytes = (size_t)n_boards * NSLICE * sizeof(float); // 512 KB
    const size_t need = ft_bytes + fft_bytes + pidx_bytes + part_bytes;

    if (ws_size < need) {
        const int grid = (n_boards + 3) / 4;
        nnue_fwd_direct<<<grid, 256, 0, stream>>>(stm_idx, nstm_idx, f_stm_idx, f_nstm_idx,
                                                  ft_w, ft_b, fft_w, fft_b, out_w, out_b,
                                                  out, n_boards);
        return;
    }

    char* wsp = (char*)d_ws;
    unsigned* ws_ft   = (unsigned*)wsp;            wsp += ft_bytes;
    unsigned* ws_fft  = (unsigned*)wsp;            wsp += fft_bytes;
    ushort4*  ws_pidx = (ushort4*)wsp;             wsp += pidx_bytes;
    float*    ws_part = (float*)wsp;

    {   // fused prep: converts + index pack in one dispatch
        const int nb_ft   = FT_IN  * 32 / 256;               // 5120
        const int nb_fft  = FFT_IN * 32 / 256;               // 80
        const int nb_pack = (n_boards * NA + 255) / 256;
        prep<<<nb_ft + nb_fft + nb_pack, 256, 0, stream>>>(
            ft_w, fft_w, stm_idx, nstm_idx, f_stm_idx, f_nstm_idx,
            ws_ft, ws_fft, ws_pidx, n_boards, nb_ft, nb_fft);
    }
    {   // sliced gather
        int groups = (n_boards + BPB - 1) / BPB;
        nnue_gather<<<groups * NSLICE, 1024, 0, stream>>>(
            (const unsigned long long*)ws_pidx, (const char*)ws_ft, (const char*)ws_fft,
            ft_b, fft_b, out_w, ws_part, n_boards);
    }
    {   // reduce partials + sigmoid
        nnue_final<<<(n_boards + 255) / 256, 256, 0, stream>>>(ws_part, out_b, out, n_boards);
    }
}